// Round 1
// baseline (2695.423 us; speedup 1.0000x reference)
//
#include <hip/hip_runtime.h>
#include <hip/hip_bf16.h>

// Problem constants
#define BB   4096
#define CC   16
#define HIDN 1024
#define NHD  16
#define HDIM 64
#define MROWS (BB*CC)   // 65536

using u16 = unsigned short;
typedef __bf16 bf16x8 __attribute__((ext_vector_type(8)));
typedef float  f32x4  __attribute__((ext_vector_type(4)));

__device__ __forceinline__ u16 f2b(float f) {
  union { __hip_bfloat16 h; u16 u; } c;
  c.h = __float2bfloat16(f);
  return c.u;
}

// ---------------------------------------------------------------------------
// Weight transpose + cast fp32 (R x C) -> bf16 (C x R)
// ---------------------------------------------------------------------------
__global__ __launch_bounds__(256) void transpose_cast(
    const float* __restrict__ src, u16* __restrict__ dst, int R, int C) {
  __shared__ float tile[32][33];
  const int bx = blockIdx.x * 32;  // col base in src
  const int by = blockIdx.y * 32;  // row base in src
  const int tx = threadIdx.x, ty = threadIdx.y;
#pragma unroll
  for (int jj = 0; jj < 32; jj += 8)
    tile[ty + jj][tx] = src[(long long)(by + ty + jj) * C + bx + tx];
  __syncthreads();
#pragma unroll
  for (int jj = 0; jj < 32; jj += 8)
    dst[(long long)(bx + ty + jj) * R + by + tx] = f2b(tile[tx][ty + jj]);
}

// ---------------------------------------------------------------------------
// Row LayerNorm fp32 -> bf16.  One block (256 thr) per row of 1024.
// ---------------------------------------------------------------------------
__global__ __launch_bounds__(256) void ln_kernel(
    const float* __restrict__ x, const float* __restrict__ g,
    const float* __restrict__ b, u16* __restrict__ out) {
  const int row = blockIdx.x;
  const int t = threadIdx.x;
  const float4 v = ((const float4*)(x + (long long)row * HIDN))[t];
  float s  = v.x + v.y + v.z + v.w;
  float sq = v.x * v.x + v.y * v.y + v.z * v.z + v.w * v.w;
#pragma unroll
  for (int off = 32; off; off >>= 1) {
    s  += __shfl_down(s, off);
    sq += __shfl_down(sq, off);
  }
  __shared__ float ws[8];
  const int w = t >> 6, lane = t & 63;
  if (lane == 0) { ws[w] = s; ws[4 + w] = sq; }
  __syncthreads();
  const float S  = ws[0] + ws[1] + ws[2] + ws[3];
  const float SQ = ws[4] + ws[5] + ws[6] + ws[7];
  const float mean = S * (1.f / HIDN);
  const float var  = SQ * (1.f / HIDN) - mean * mean;
  const float rstd = rsqrtf(var + 1e-5f);
  const float4 gg = ((const float4*)g)[t];
  const float4 bb = ((const float4*)b)[t];
  ushort4 o;
  o.x = f2b((v.x - mean) * rstd * gg.x + bb.x);
  o.y = f2b((v.y - mean) * rstd * gg.y + bb.y);
  o.z = f2b((v.z - mean) * rstd * gg.z + bb.z);
  o.w = f2b((v.w - mean) * rstd * gg.w + bb.w);
  ((ushort4*)(out + (long long)row * HIDN))[t] = o;
}

// ---------------------------------------------------------------------------
// GEMM: C[M,N] = A[M,K] @ B[K,N], A bf16 row-major, BT = B^T bf16 (N x K).
// 128x128 tile, BK=64, 4 waves (2x2), each wave 4x4 of 16x16x32 MFMA.
// global_load_lds (16B) staging with XOR chunk swizzle to kill bank conflicts.
// EPI: 0 = bias -> bf16 ; 1 = bias + ct_key gather -> bf16 ;
//      2 = bias + fp32 residual -> fp32 ; 3 = bias + ELU -> bf16
// ---------------------------------------------------------------------------
#define BM 128
#define BN 128
#define BK 64

template <int EPI>
__global__ __launch_bounds__(256, 2) void gemm_bt(
    const u16* __restrict__ A, const u16* __restrict__ BT, int K,
    const float* __restrict__ bias, const float* __restrict__ resid,
    const int* __restrict__ ctype, const float* __restrict__ ct_key,
    float* __restrict__ outF, u16* __restrict__ outB, int N) {
  __shared__ u16 As[BM * BK];  // 16 KB, stored as 16B chunks, kc XOR (row&7)
  __shared__ u16 Bs[BN * BK];  // 16 KB

  const int t = threadIdx.x;
  const int lane = t & 63;
  const int w = t >> 6;
  const int wm = w & 1, wn = w >> 1;
  const int lane15 = lane & 15;
  const int quad = lane >> 4;
  const int mblk = blockIdx.x, nblk = blockIdx.y;

  const long long Abase = (long long)mblk * BM * K;
  const long long Bbase = (long long)nblk * BN * K;

  f32x4 acc[4][4] = {};

  for (int kk = 0; kk < K; kk += BK) {
    // ---- stage A & B tiles: 1024 chunks of 16B each, 4 per thread per tile
#pragma unroll
    for (int j = 0; j < 4; ++j) {
      const int c = j * 256 + t;
      const int row = c >> 3;
      const int kcs = c & 7;
      const int kct = kcs ^ (row & 7);  // swizzle on the global side
      const u16* gA = A + Abase + (long long)row * K + kk + kct * 8;
      const u16* gB = BT + Bbase + (long long)row * K + kk + kct * 8;
      __builtin_amdgcn_global_load_lds(
          (const __attribute__((address_space(1))) void*)gA,
          (__attribute__((address_space(3))) void*)(As + c * 8), 16, 0, 0);
      __builtin_amdgcn_global_load_lds(
          (const __attribute__((address_space(1))) void*)gB,
          (__attribute__((address_space(3))) void*)(Bs + c * 8), 16, 0, 0);
    }
    __syncthreads();

    // ---- compute: two K-steps of 32
#pragma unroll
    for (int k0 = 0; k0 < 2; ++k0) {
      const int kc = k0 * 4 + quad;
      bf16x8 af[4], bfr[4];
#pragma unroll
      for (int im = 0; im < 4; ++im) {
        const int m = wm * 64 + im * 16 + lane15;
        af[im] = *(const bf16x8*)(As + (m * 8 + (kc ^ (m & 7))) * 8);
      }
#pragma unroll
      for (int in = 0; in < 4; ++in) {
        const int n = wn * 64 + in * 16 + lane15;
        bfr[in] = *(const bf16x8*)(Bs + (n * 8 + (kc ^ (n & 7))) * 8);
      }
#pragma unroll
      for (int im = 0; im < 4; ++im)
#pragma unroll
        for (int in = 0; in < 4; ++in)
          acc[im][in] = __builtin_amdgcn_mfma_f32_16x16x32_bf16(
              af[im], bfr[in], acc[im][in], 0, 0, 0);
    }
    __syncthreads();
  }

  // ---- epilogue.  C/D layout: col = lane&15, row = quad*4 + r
  const int rowBase = mblk * BM + wm * 64 + quad * 4;
  const int colBase = nblk * BN + wn * 64 + lane15;
#pragma unroll
  for (int in = 0; in < 4; ++in) {
    const int col = colBase + in * 16;
    const float bv = bias[col];
#pragma unroll
    for (int im = 0; im < 4; ++im) {
#pragma unroll
      for (int r = 0; r < 4; ++r) {
        const int row = rowBase + im * 16 + r;
        float v = acc[im][in][r] + bv;
        const long long oidx = (long long)row * N + col;
        if constexpr (EPI == 1) {
          v += ct_key[(long long)ctype[row >> 4] * HIDN + col];
          outB[oidx] = f2b(v);
        } else if constexpr (EPI == 2) {
          outF[oidx] = v + resid[oidx];
        } else if constexpr (EPI == 3) {
          v = v > 0.f ? v : __expf(v) - 1.f;
          outB[oidx] = f2b(v);
        } else {
          outB[oidx] = f2b(v);
        }
      }
    }
  }
}

// ---------------------------------------------------------------------------
// Per-batch attention. 1 block / batch, thread = (head h, query i).
// Q,K,V bf16 (MROWS x 1024). out bf16 (MROWS x 1024).
// ---------------------------------------------------------------------------
__global__ __launch_bounds__(256) void attn_kernel(
    const u16* __restrict__ Q, const u16* __restrict__ Kb,
    const u16* __restrict__ Vb, const int* __restrict__ cancer_type,
    const int* __restrict__ channel_active,
    const float* __restrict__ ct_bias_emb, u16* __restrict__ out) {
  __shared__ u16 Ks[CC * HIDN];  // 32 KB
  __shared__ u16 Vs[CC * HIDN];  // 32 KB
  const int b = blockIdx.x;
  const int t = threadIdx.x;

  const u16* Kg = Kb + (long long)b * CC * HIDN;
  const u16* Vg = Vb + (long long)b * CC * HIDN;
#pragma unroll
  for (int j = 0; j < 8; ++j) {
    const int c = j * 256 + t;
    ((float4*)Ks)[c] = ((const float4*)Kg)[c];
    ((float4*)Vs)[c] = ((const float4*)Vg)[c];
  }
  __syncthreads();

  const int h = t >> 4, i = t & 15;
  const int ct = cancer_type[b];
  const float* ctb = ct_bias_emb + ct * (CC * CC) + i * CC;

  // load q row (64 floats)
  float q[HDIM];
  const u16* qg = Q + ((long long)(b * CC + i) * HIDN + h * HDIM);
#pragma unroll
  for (int c = 0; c < 8; ++c) {
    const bf16x8 v = *(const bf16x8*)(qg + c * 8);
#pragma unroll
    for (int e = 0; e < 8; ++e) q[c * 8 + e] = (float)v[e];
  }

  // scores
  float s[CC];
#pragma unroll
  for (int j = 0; j < CC; ++j) {
    const u16* kr = Ks + j * HIDN + h * HDIM;
    float a = 0.f;
#pragma unroll
    for (int c = 0; c < 8; ++c) {
      const bf16x8 kv = *(const bf16x8*)(kr + c * 8);
#pragma unroll
      for (int e = 0; e < 8; ++e) a += q[c * 8 + e] * (float)kv[e];
    }
    a = a * 0.125f + 0.1f * ctb[j];
    if (channel_active[b * CC + j] == 0) a = -__builtin_inff();
    s[j] = a;
  }

  // softmax with all-masked -> zeros (nan_to_num)
  float mx = -__builtin_inff();
#pragma unroll
  for (int j = 0; j < CC; ++j) mx = fmaxf(mx, s[j]);
  float p[CC];
  float sum = 0.f;
  const bool dead = (mx == -__builtin_inff());
#pragma unroll
  for (int j = 0; j < CC; ++j) {
    p[j] = dead ? 0.f : __expf(s[j] - mx);
    sum += p[j];
  }
  const float inv = sum > 0.f ? 1.f / sum : 0.f;

  // P @ V
  float o[HDIM] = {};
#pragma unroll
  for (int j = 0; j < CC; ++j) {
    const float pw = p[j] * inv;
    const u16* vr = Vs + j * HIDN + h * HDIM;
#pragma unroll
    for (int c = 0; c < 8; ++c) {
      const bf16x8 vv = *(const bf16x8*)(vr + c * 8);
#pragma unroll
      for (int e = 0; e < 8; ++e) o[c * 8 + e] += pw * (float)vv[e];
    }
  }

  u16* og = out + ((long long)(b * CC + i) * HIDN + h * HDIM);
#pragma unroll
  for (int c = 0; c < 8; ++c) {
    uint4 u;
    u.x = (unsigned)f2b(o[c * 8 + 0]) | ((unsigned)f2b(o[c * 8 + 1]) << 16);
    u.y = (unsigned)f2b(o[c * 8 + 2]) | ((unsigned)f2b(o[c * 8 + 3]) << 16);
    u.z = (unsigned)f2b(o[c * 8 + 4]) | ((unsigned)f2b(o[c * 8 + 5]) << 16);
    u.w = (unsigned)f2b(o[c * 8 + 6]) | ((unsigned)f2b(o[c * 8 + 7]) << 16);
    ((uint4*)og)[c] = u;
  }
}

// ---------------------------------------------------------------------------
extern "C" void kernel_launch(void* const* d_in, const int* in_sizes, int n_in,
                              void* d_out, int out_size, void* d_ws,
                              size_t ws_size, hipStream_t stream) {
  const float* x            = (const float*)d_in[0];
  const int*   cancer_type  = (const int*)d_in[1];
  const int*   channel_act  = (const int*)d_in[2];
  const float* Wq = (const float*)d_in[3];  const float* bq = (const float*)d_in[4];
  const float* Wk = (const float*)d_in[5];  const float* bk = (const float*)d_in[6];
  const float* Wv = (const float*)d_in[7];  const float* bv = (const float*)d_in[8];
  const float* Wo = (const float*)d_in[9];  const float* bo = (const float*)d_in[10];
  const float* ct_bias_emb = (const float*)d_in[11];
  const float* ct_key_emb  = (const float*)d_in[12];
  const float* ln1_g = (const float*)d_in[13]; const float* ln1_b = (const float*)d_in[14];
  const float* ln2_g = (const float*)d_in[15]; const float* ln2_b = (const float*)d_in[16];
  const float* W1 = (const float*)d_in[17]; const float* b1 = (const float*)d_in[18];
  const float* W2 = (const float*)d_in[19]; const float* b2 = (const float*)d_in[20];
  float* out = (float*)d_out;

  // workspace layout (528 MB)
  u16* WqT = (u16*)d_ws;
  u16* WkT = WqT + (size_t)1024 * 1024;
  u16* WvT = WkT + (size_t)1024 * 1024;
  u16* WoT = WvT + (size_t)1024 * 1024;
  u16* W1T = WoT + (size_t)1024 * 1024;   // 2048 x 1024
  u16* W2T = W1T + (size_t)2048 * 1024;   // 1024 x 2048
  u16* normed = W2T + (size_t)1024 * 2048;
  u16* Qb = normed + (size_t)MROWS * HIDN;
  u16* Kb = Qb + (size_t)MROWS * HIDN;
  u16* Vb = Kb + (size_t)MROWS * HIDN;
  u16* attnO = normed;        // reuse (normed dead after QKV)
  u16* h2    = Qb;            // reuse (Q dead after attention)
  u16* act   = Kb;            // 65536 x 2048 spans Kb+Vb (dead after attention)
  float* x2  = (float*)d_out; // residual stream lives in d_out until FFN2

  const dim3 tb(32, 8);
  transpose_cast<<<dim3(32, 32), tb, 0, stream>>>(Wq, WqT, 1024, 1024);
  transpose_cast<<<dim3(32, 32), tb, 0, stream>>>(Wk, WkT, 1024, 1024);
  transpose_cast<<<dim3(32, 32), tb, 0, stream>>>(Wv, WvT, 1024, 1024);
  transpose_cast<<<dim3(32, 32), tb, 0, stream>>>(Wo, WoT, 1024, 1024);
  transpose_cast<<<dim3(64, 32), tb, 0, stream>>>(W1, W1T, 1024, 2048);
  transpose_cast<<<dim3(32, 64), tb, 0, stream>>>(W2, W2T, 2048, 1024);

  ln_kernel<<<MROWS, 256, 0, stream>>>(x, ln1_g, ln1_b, normed);

  gemm_bt<0><<<dim3(512, 8), 256, 0, stream>>>(normed, WqT, 1024, bq, nullptr,
                                               nullptr, nullptr, nullptr, Qb, 1024);
  gemm_bt<1><<<dim3(512, 8), 256, 0, stream>>>(normed, WkT, 1024, bk, nullptr,
                                               cancer_type, ct_key_emb, nullptr, Kb, 1024);
  gemm_bt<0><<<dim3(512, 8), 256, 0, stream>>>(normed, WvT, 1024, bv, nullptr,
                                               nullptr, nullptr, nullptr, Vb, 1024);

  attn_kernel<<<BB, 256, 0, stream>>>(Qb, Kb, Vb, cancer_type, channel_act,
                                      ct_bias_emb, attnO);

  gemm_bt<2><<<dim3(512, 8), 256, 0, stream>>>(attnO, WoT, 1024, bo, x,
                                               nullptr, nullptr, x2, nullptr, 1024);

  ln_kernel<<<MROWS, 256, 0, stream>>>(x2, ln2_g, ln2_b, h2);

  gemm_bt<3><<<dim3(512, 16), 256, 0, stream>>>(h2, W1T, 1024, b1, nullptr,
                                                nullptr, nullptr, nullptr, act, 2048);
  gemm_bt<2><<<dim3(512, 8), 256, 0, stream>>>(act, W2T, 2048, b2, x2,
                                               nullptr, nullptr, out, nullptr, 1024);
}

// Round 2
// 2430.375 us; speedup vs baseline: 1.1091x; 1.1091x over previous
//
#include <hip/hip_runtime.h>
#include <hip/hip_bf16.h>

// Problem constants
#define BB   4096
#define CC   16
#define HIDN 1024
#define NHD  16
#define HDIM 64
#define MROWS (BB*CC)   // 65536
#define QKVN 3072

using u16 = unsigned short;
typedef __bf16 bf16x8 __attribute__((ext_vector_type(8)));
typedef float  f32x4  __attribute__((ext_vector_type(4)));

__device__ __forceinline__ u16 f2b(float f) {
  union { __hip_bfloat16 h; u16 u; } c;
  c.h = __float2bfloat16(f);
  return c.u;
}

// ---------------------------------------------------------------------------
// Weight transpose + cast fp32 (R x C) -> bf16 (C x R)
// ---------------------------------------------------------------------------
__global__ __launch_bounds__(256) void transpose_cast(
    const float* __restrict__ src, u16* __restrict__ dst, int R, int C) {
  __shared__ float tile[32][33];
  const int bx = blockIdx.x * 32;  // col base in src
  const int by = blockIdx.y * 32;  // row base in src
  const int tx = threadIdx.x, ty = threadIdx.y;
#pragma unroll
  for (int jj = 0; jj < 32; jj += 8)
    tile[ty + jj][tx] = src[(long long)(by + ty + jj) * C + bx + tx];
  __syncthreads();
#pragma unroll
  for (int jj = 0; jj < 32; jj += 8)
    dst[(long long)(bx + ty + jj) * R + by + tx] = f2b(tile[tx][ty + jj]);
}

// ---------------------------------------------------------------------------
// Row LayerNorm fp32 -> bf16.  One block (256 thr) per row of 1024.
// ---------------------------------------------------------------------------
__global__ __launch_bounds__(256) void ln_kernel(
    const float* __restrict__ x, const float* __restrict__ g,
    const float* __restrict__ b, u16* __restrict__ out) {
  const int row = blockIdx.x;
  const int t = threadIdx.x;
  const float4 v = ((const float4*)(x + (long long)row * HIDN))[t];
  float s  = v.x + v.y + v.z + v.w;
  float sq = v.x * v.x + v.y * v.y + v.z * v.z + v.w * v.w;
#pragma unroll
  for (int off = 32; off; off >>= 1) {
    s  += __shfl_down(s, off);
    sq += __shfl_down(sq, off);
  }
  __shared__ float ws[8];
  const int w = t >> 6, lane = t & 63;
  if (lane == 0) { ws[w] = s; ws[4 + w] = sq; }
  __syncthreads();
  const float S  = ws[0] + ws[1] + ws[2] + ws[3];
  const float SQ = ws[4] + ws[5] + ws[6] + ws[7];
  const float mean = S * (1.f / HIDN);
  const float var  = SQ * (1.f / HIDN) - mean * mean;
  const float rstd = rsqrtf(var + 1e-5f);
  const float4 gg = ((const float4*)g)[t];
  const float4 bb = ((const float4*)b)[t];
  ushort4 o;
  o.x = f2b((v.x - mean) * rstd * gg.x + bb.x);
  o.y = f2b((v.y - mean) * rstd * gg.y + bb.y);
  o.z = f2b((v.z - mean) * rstd * gg.z + bb.z);
  o.w = f2b((v.w - mean) * rstd * gg.w + bb.w);
  ((ushort4*)(out + (long long)row * HIDN))[t] = o;
}

// ---------------------------------------------------------------------------
// GEMM: C[M,N] = A[M,K] @ B[K,N], A bf16 row-major, BT = B^T bf16 (N x K).
// 128x128 tile, BK=64, 4 waves (2x2), each wave 4x4 of 16x16x32 MFMA.
// grid = (N/BN fast, M/BM slow) so N-groups sharing an A-row-block run in a
// tight temporal window -> A streams from HBM once (L3 holds the window).
// EPI: 1 = fused QKV (per-block bias select + ct_key on K cols) -> bf16
//      2 = bias + fp32 residual -> fp32 ; 3 = bias + ELU -> bf16
// ---------------------------------------------------------------------------
#define BM 128
#define BN 128
#define BK 64

template <int EPI>
__global__ __launch_bounds__(256, 2) void gemm_bt(
    const u16* __restrict__ A, const u16* __restrict__ BT, int K,
    const float* __restrict__ bias, const float* __restrict__ bias2,
    const float* __restrict__ bias3, const float* __restrict__ resid,
    const int* __restrict__ ctype, const float* __restrict__ ct_key,
    float* __restrict__ outF, u16* __restrict__ outB, int N) {
  __shared__ u16 As[BM * BK];  // 16 KB, stored as 16B chunks, kc XOR (row&7)
  __shared__ u16 Bs[BN * BK];  // 16 KB

  const int t = threadIdx.x;
  const int lane = t & 63;
  const int w = t >> 6;
  const int wm = w & 1, wn = w >> 1;
  const int lane15 = lane & 15;
  const int quad = lane >> 4;
  const int nblk = blockIdx.x, mblk = blockIdx.y;  // N fast, M slow

  const long long Abase = (long long)mblk * BM * K;
  const long long Bbase = (long long)nblk * BN * K;

  f32x4 acc[4][4] = {};

  for (int kk = 0; kk < K; kk += BK) {
    // ---- stage A & B tiles: 1024 chunks of 16B each, 4 per thread per tile
#pragma unroll
    for (int j = 0; j < 4; ++j) {
      const int c = j * 256 + t;
      const int row = c >> 3;
      const int kcs = c & 7;
      const int kct = kcs ^ (row & 7);  // swizzle on the global side
      const u16* gA = A + Abase + (long long)row * K + kk + kct * 8;
      const u16* gB = BT + Bbase + (long long)row * K + kk + kct * 8;
      __builtin_amdgcn_global_load_lds(
          (const __attribute__((address_space(1))) void*)gA,
          (__attribute__((address_space(3))) void*)(As + c * 8), 16, 0, 0);
      __builtin_amdgcn_global_load_lds(
          (const __attribute__((address_space(1))) void*)gB,
          (__attribute__((address_space(3))) void*)(Bs + c * 8), 16, 0, 0);
    }
    __syncthreads();

    // ---- compute: two K-steps of 32
#pragma unroll
    for (int k0 = 0; k0 < 2; ++k0) {
      const int kc = k0 * 4 + quad;
      bf16x8 af[4], bfr[4];
#pragma unroll
      for (int im = 0; im < 4; ++im) {
        const int m = wm * 64 + im * 16 + lane15;
        af[im] = *(const bf16x8*)(As + (m * 8 + (kc ^ (m & 7))) * 8);
      }
#pragma unroll
      for (int in = 0; in < 4; ++in) {
        const int n = wn * 64 + in * 16 + lane15;
        bfr[in] = *(const bf16x8*)(Bs + (n * 8 + (kc ^ (n & 7))) * 8);
      }
#pragma unroll
      for (int im = 0; im < 4; ++im)
#pragma unroll
        for (int in = 0; in < 4; ++in)
          acc[im][in] = __builtin_amdgcn_mfma_f32_16x16x32_bf16(
              af[im], bfr[in], acc[im][in], 0, 0, 0);
    }
    __syncthreads();
  }

  // ---- epilogue.  C/D layout: col = lane&15, row = quad*4 + r
  const int rowBase = mblk * BM + wm * 64 + quad * 4;
  const int colBase = nblk * BN + wn * 64 + lane15;

  // EPI==1: block-uniform sub-matrix select (BN=128 divides 1024)
  const float* bsel = bias;
  bool addct = false;
  if constexpr (EPI == 1) {
    const int sub = nblk >> 3;
    bsel = (sub == 0) ? bias : (sub == 1 ? bias2 : bias3);
    addct = (sub == 1);
  }

#pragma unroll
  for (int in = 0; in < 4; ++in) {
    const int col = colBase + in * 16;
    float bv;
    if constexpr (EPI == 1) {
      bv = bsel[col & 1023];
    } else {
      bv = bias[col];
    }
#pragma unroll
    for (int im = 0; im < 4; ++im) {
#pragma unroll
      for (int r = 0; r < 4; ++r) {
        const int row = rowBase + im * 16 + r;
        float v = acc[im][in][r] + bv;
        const long long oidx = (long long)row * N + col;
        if constexpr (EPI == 1) {
          if (addct) v += ct_key[(long long)ctype[row >> 4] * HIDN + (col & 1023)];
          outB[oidx] = f2b(v);
        } else if constexpr (EPI == 2) {
          outF[oidx] = v + resid[oidx];
        } else if constexpr (EPI == 3) {
          v = v > 0.f ? v : __expf(v) - 1.f;
          outB[oidx] = f2b(v);
        } else {
          outB[oidx] = f2b(v);
        }
      }
    }
  }
}

// ---------------------------------------------------------------------------
// Per-batch attention. 1 block / batch, thread = (head h, query i).
// QKV bf16 interleaved (MROWS x 3072): [Q(1024) | K(1024) | V(1024)] per row.
// out bf16 (MROWS x 1024).
// ---------------------------------------------------------------------------
__global__ __launch_bounds__(256) void attn_kernel(
    const u16* __restrict__ QKV, const int* __restrict__ cancer_type,
    const int* __restrict__ channel_active,
    const float* __restrict__ ct_bias_emb, u16* __restrict__ out) {
  __shared__ u16 Ks[CC * HIDN];  // 32 KB
  __shared__ u16 Vs[CC * HIDN];  // 32 KB
  const int b = blockIdx.x;
  const int t = threadIdx.x;

#pragma unroll
  for (int j = 0; j < 8; ++j) {
    const int c = j * 256 + t;     // c = row*128 + off
    const int row = c >> 7;
    const int off = c & 127;
    const long long base = (long long)(b * CC + row) * QKVN;
    ((float4*)Ks)[c] = *(const float4*)(QKV + base + 1024 + off * 8);
    ((float4*)Vs)[c] = *(const float4*)(QKV + base + 2048 + off * 8);
  }
  __syncthreads();

  const int h = t >> 4, i = t & 15;
  const int ct = cancer_type[b];
  const float* ctb = ct_bias_emb + ct * (CC * CC) + i * CC;

  // load q row (64 floats)
  float q[HDIM];
  const u16* qg = QKV + ((long long)(b * CC + i) * QKVN + h * HDIM);
#pragma unroll
  for (int c = 0; c < 8; ++c) {
    const bf16x8 v = *(const bf16x8*)(qg + c * 8);
#pragma unroll
    for (int e = 0; e < 8; ++e) q[c * 8 + e] = (float)v[e];
  }

  // scores
  float s[CC];
#pragma unroll
  for (int j = 0; j < CC; ++j) {
    const u16* kr = Ks + j * HIDN + h * HDIM;
    float a = 0.f;
#pragma unroll
    for (int c = 0; c < 8; ++c) {
      const bf16x8 kv = *(const bf16x8*)(kr + c * 8);
#pragma unroll
      for (int e = 0; e < 8; ++e) a += q[c * 8 + e] * (float)kv[e];
    }
    a = a * 0.125f + 0.1f * ctb[j];
    if (channel_active[b * CC + j] == 0) a = -__builtin_inff();
    s[j] = a;
  }

  // softmax with all-masked -> zeros (nan_to_num)
  float mx = -__builtin_inff();
#pragma unroll
  for (int j = 0; j < CC; ++j) mx = fmaxf(mx, s[j]);
  float p[CC];
  float sum = 0.f;
  const bool dead = (mx == -__builtin_inff());
#pragma unroll
  for (int j = 0; j < CC; ++j) {
    p[j] = dead ? 0.f : __expf(s[j] - mx);
    sum += p[j];
  }
  const float inv = sum > 0.f ? 1.f / sum : 0.f;

  // P @ V
  float o[HDIM] = {};
#pragma unroll
  for (int j = 0; j < CC; ++j) {
    const float pw = p[j] * inv;
    const u16* vr = Vs + j * HIDN + h * HDIM;
#pragma unroll
    for (int c = 0; c < 8; ++c) {
      const bf16x8 vv = *(const bf16x8*)(vr + c * 8);
#pragma unroll
      for (int e = 0; e < 8; ++e) o[c * 8 + e] += pw * (float)vv[e];
    }
  }

  u16* og = out + ((long long)(b * CC + i) * HIDN + h * HDIM);
#pragma unroll
  for (int c = 0; c < 8; ++c) {
    uint4 u;
    u.x = (unsigned)f2b(o[c * 8 + 0]) | ((unsigned)f2b(o[c * 8 + 1]) << 16);
    u.y = (unsigned)f2b(o[c * 8 + 2]) | ((unsigned)f2b(o[c * 8 + 3]) << 16);
    u.z = (unsigned)f2b(o[c * 8 + 4]) | ((unsigned)f2b(o[c * 8 + 5]) << 16);
    u.w = (unsigned)f2b(o[c * 8 + 6]) | ((unsigned)f2b(o[c * 8 + 7]) << 16);
    ((uint4*)og)[c] = u;
  }
}

// ---------------------------------------------------------------------------
extern "C" void kernel_launch(void* const* d_in, const int* in_sizes, int n_in,
                              void* d_out, int out_size, void* d_ws,
                              size_t ws_size, hipStream_t stream) {
  const float* x            = (const float*)d_in[0];
  const int*   cancer_type  = (const int*)d_in[1];
  const int*   channel_act  = (const int*)d_in[2];
  const float* Wq = (const float*)d_in[3];  const float* bq = (const float*)d_in[4];
  const float* Wk = (const float*)d_in[5];  const float* bk = (const float*)d_in[6];
  const float* Wv = (const float*)d_in[7];  const float* bv = (const float*)d_in[8];
  const float* Wo = (const float*)d_in[9];  const float* bo = (const float*)d_in[10];
  const float* ct_bias_emb = (const float*)d_in[11];
  const float* ct_key_emb  = (const float*)d_in[12];
  const float* ln1_g = (const float*)d_in[13]; const float* ln1_b = (const float*)d_in[14];
  const float* ln2_g = (const float*)d_in[15]; const float* ln2_b = (const float*)d_in[16];
  const float* W1 = (const float*)d_in[17]; const float* b1 = (const float*)d_in[18];
  const float* W2 = (const float*)d_in[19]; const float* b2 = (const float*)d_in[20];
  float* out = (float*)d_out;

  // workspace layout
  u16* WqkvT = (u16*)d_ws;                      // 3072 x 1024
  u16* WoT = WqkvT + (size_t)QKVN * 1024;       // 1024 x 1024
  u16* W1T = WoT + (size_t)1024 * 1024;         // 2048 x 1024
  u16* W2T = W1T + (size_t)2048 * 1024;         // 1024 x 2048
  u16* normed = W2T + (size_t)1024 * 2048;      // 65536 x 1024
  u16* QKV = normed + (size_t)MROWS * HIDN;     // 65536 x 3072
  u16* attnO = normed;                // reuse (normed dead after QKV gemm)
  u16* h2    = QKV;                   // reuse (QKV dead after attention)
  u16* act   = QKV + (size_t)MROWS * HIDN;  // 65536 x 2048 in QKV region
  float* x2  = (float*)d_out;         // residual stream lives in d_out

  const dim3 tb(32, 8);
  transpose_cast<<<dim3(32, 32), tb, 0, stream>>>(Wq, WqkvT, 1024, 1024);
  transpose_cast<<<dim3(32, 32), tb, 0, stream>>>(Wk, WqkvT + (size_t)1024 * 1024, 1024, 1024);
  transpose_cast<<<dim3(32, 32), tb, 0, stream>>>(Wv, WqkvT + (size_t)2048 * 1024, 1024, 1024);
  transpose_cast<<<dim3(32, 32), tb, 0, stream>>>(Wo, WoT, 1024, 1024);
  transpose_cast<<<dim3(64, 32), tb, 0, stream>>>(W1, W1T, 1024, 2048);
  transpose_cast<<<dim3(32, 64), tb, 0, stream>>>(W2, W2T, 2048, 1024);

  ln_kernel<<<MROWS, 256, 0, stream>>>(x, ln1_g, ln1_b, normed);

  // fused QKV: C = normed @ [Wq|Wk|Wv]  (65536 x 3072)
  gemm_bt<1><<<dim3(24, 512), 256, 0, stream>>>(
      normed, WqkvT, 1024, bq, bk, bv, nullptr, cancer_type, ct_key_emb,
      nullptr, QKV, QKVN);

  attn_kernel<<<BB, 256, 0, stream>>>(QKV, cancer_type, channel_act,
                                      ct_bias_emb, attnO);

  gemm_bt<2><<<dim3(8, 512), 256, 0, stream>>>(
      attnO, WoT, 1024, bo, nullptr, nullptr, x, nullptr, nullptr,
      x2, nullptr, 1024);

  ln_kernel<<<MROWS, 256, 0, stream>>>(x2, ln2_g, ln2_b, h2);

  gemm_bt<3><<<dim3(16, 512), 256, 0, stream>>>(
      h2, W1T, 1024, b1, nullptr, nullptr, nullptr, nullptr, nullptr,
      nullptr, act, 2048);

  gemm_bt<2><<<dim3(8, 512), 256, 0, stream>>>(
      act, W2T, 2048, b2, nullptr, nullptr, x2, nullptr, nullptr,
      out, nullptr, 1024);
}